// Round 2
// baseline (62.916 us; speedup 1.0000x reference)
//
#include <hip/hip_runtime.h>
#include <hip/hip_bf16.h>

// RipsLayer: gather-only persistence diagram assembly. All fp32 I/O per the
// reference (X float32, indices int32, outputs float32).
// Sizes fixed by the reference:
#define F0   8191   // finite dim-0 pairs
#define F1   4096   // finite dim-1 pairs
#define E1   8      // essential dim-1 classes
// Output layout (flat, return order):
//   [0 .. 2*F0)              finite_dgm0 [F0,2]  (birth=0, death)
//   [2*F0]                   essential_dgm0 [1,1] = 0
//   [2*F0+1 .. +2*F1)        finite_dgm1 [F1,2]  (idx1_finite viewed [2*F1,2])
//   [2*F0+1+2*F1 .. +E1)     essential_dgm1 [E1,1]
// Total = 24583 fp32 elements.

__device__ __forceinline__ float pdist3(const float* __restrict__ X, int i, int j) {
    float dx = X[i * 3 + 0] - X[j * 3 + 0];
    float dy = X[i * 3 + 1] - X[j * 3 + 1];
    float dz = X[i * 3 + 2] - X[j * 3 + 2];
    return sqrtf(dx * dx + dy * dy + dz * dz);
}

__global__ void __launch_bounds__(256)
rips_kernel(const float* __restrict__ X,
            const int* __restrict__ idx0f,   // [F0,3]
            const int* __restrict__ idx1f,   // [F1,4] == [2*F1,2]
            const int* __restrict__ idx1e,   // [E1,2]
            float* __restrict__ out) {
    int t = blockIdx.x * blockDim.x + threadIdx.x;

    if (t < 2 * F0) {
        // finite_dgm0: even col = birth (0), odd col = death = DX[e1,e2]
        if (t & 1) {
            int r = t >> 1;
            out[t] = pdist3(X, idx0f[r * 3 + 1], idx0f[r * 3 + 2]);
        } else {
            out[t] = 0.0f;
        }
        return;
    }
    t -= 2 * F0;

    if (t == 0) {  // essential_dgm0
        out[2 * F0] = 0.0f;
        return;
    }
    t -= 1;

    if (t < 2 * F1) {  // finite_dgm1 (flat over the [2*F1,2] pair view)
        out[2 * F0 + 1 + t] = pdist3(X, idx1f[t * 2 + 0], idx1f[t * 2 + 1]);
        return;
    }
    t -= 2 * F1;

    if (t < E1) {  // essential_dgm1
        out[2 * F0 + 1 + 2 * F1 + t] = pdist3(X, idx1e[t * 2 + 0], idx1e[t * 2 + 1]);
    }
}

extern "C" void kernel_launch(void* const* d_in, const int* in_sizes, int n_in,
                              void* d_out, int out_size, void* d_ws, size_t ws_size,
                              hipStream_t stream) {
    const float* X   = (const float*)d_in[0];   // [8192,3] fp32
    const int* idx0f = (const int*)d_in[1];     // [F0,3]
    // d_in[2] = idx0_essential — values unused (output region is zeros)
    const int* idx1f = (const int*)d_in[3];     // [F1,4]
    const int* idx1e = (const int*)d_in[4];     // [E1,2]
    float* out       = (float*)d_out;

    const int total = 2 * F0 + 1 + 2 * F1 + E1;  // 24583
    const int block = 256;
    const int grid  = (total + block - 1) / block;  // 97
    rips_kernel<<<grid, block, 0, stream>>>(X, idx0f, idx1f, idx1e, out);
}